// Round 1
// baseline (41.646 us; speedup 1.0000x reference)
//
#include <hip/hip_runtime.h>

#define BIG_DELTA 1e10f
#define P 192  // points per ray (fixed by the reference)

// One wave per ray; 192 points = 64 lanes x 3 points (full lane utilization,
// vs the previous 48x4 + 16 idle-lane layout).
__global__ __launch_bounds__(256) void volrender_kernel(
    const float* __restrict__ depth,    // (R, 192)
    const float* __restrict__ density,  // (R, 192, 1)
    const float* __restrict__ feature,  // (R, 192, 3)
    float* __restrict__ out,            // (R, 4)
    int num_rays)
{
    const int lane = threadIdx.x & 63;
    const int ray  = blockIdx.x * (blockDim.x >> 6) + (threadIdx.x >> 6);
    if (ray >= num_rays) return;

    // Lane l owns points p = 3l, 3l+1, 3l+2.
    const float* dP = depth   + (size_t)ray * P + 3 * lane;
    const float* sP = density + (size_t)ray * P + 3 * lane;
    const float* fP = feature + (size_t)ray * (P * 3) + 9 * lane;

    // Contiguous per-lane chunks; adjacent lanes are contiguous in memory so
    // each merged wide load is fully coalesced (LSV merges these to
    // dwordx3 / dwordx4+dwordx4+dword — global loads need only dword align).
    float d0 = dP[0], d1 = dP[1], d2 = dP[2];
    float s0 = sP[0], s1 = sP[1], s2 = sP[2];
    float f0 = fP[0], f1 = fP[1], f2 = fP[2];
    float f3 = fP[3], f4 = fP[4], f5 = fP[5];
    float f6 = fP[6], f7 = fP[7], f8 = fP[8];

    // deltas: next depth minus current; lane boundary via shfl; the global
    // last point (lane 63, elem 2) gets the BIG_DELTA sentinel.
    float dn = __shfl_down(d0, 1);
    float delta0 = d1 - d0;
    float delta1 = d2 - d1;
    float delta2 = (lane == 63) ? BIG_DELTA : (dn - d2);

    float tm0 = delta0 * s0;
    float tm1 = delta1 * s1;
    float tm2 = delta2 * s2;

    // in-lane inclusive prefix
    float p0 = tm0;
    float p1 = p0 + tm1;
    float p2 = p1 + tm2;

    // wave-wide inclusive scan of lane totals (Hillis-Steele, 6 steps)
    float c = p2;
    #pragma unroll
    for (int off = 1; off < 64; off <<= 1) {
        float u = __shfl_up(c, off);
        if (lane >= off) c += u;
    }
    // Exclusive scan via up-shift — NOT (c - p2): lane 63's p2 holds the
    // 1e10 sentinel term and subtracting two ~1e10 values annihilates the
    // true prefix in f32. shfl_up takes lane 62's inclusive value instead.
    float excl = __shfl_up(c, 1);
    if (lane == 0) excl = 0.0f;

    // w_i = exp(-inclusive cumsum) * (1 - exp(-tm_i))
    float w0 = __expf(-(excl + p0)) * (1.0f - __expf(-tm0));
    float w1 = __expf(-(excl + p1)) * (1.0f - __expf(-tm1));
    float w2 = __expf(-(excl + p2)) * (1.0f - __expf(-tm2));

    float accR = w0 * f0 + w1 * f3 + w2 * f6;
    float accG = w0 * f1 + w1 * f4 + w2 * f7;
    float accB = w0 * f2 + w1 * f5 + w2 * f8;
    float accD = w0 * d0 + w1 * d1 + w2 * d2;

    // Reduction, 12 shfls instead of 24:
    // (1) butterfly offsets {1,2} on all four accumulators -> every lane
    //     holds its aligned 4-lane-group sum of each value.
    #pragma unroll
    for (int off = 1; off <= 2; off <<= 1) {
        accR += __shfl_xor(accR, off);
        accG += __shfl_xor(accG, off);
        accB += __shfl_xor(accB, off);
        accD += __shfl_xor(accD, off);
    }
    // (2) each lane keeps one value by lane&3; butterfly offsets {4,8,16,32}
    //     only combine lanes with equal lane&3, so the classes stay separate.
    const int m = lane & 3;
    float v = (m == 0) ? accR : (m == 1) ? accG : (m == 2) ? accB : accD;
    #pragma unroll
    for (int off = 4; off < 64; off <<= 1) {
        v += __shfl_xor(v, off);
    }
    // lanes 0..3 hold the R,G,B,D totals -> one coalesced 16B store.
    if (lane < 4) out[(size_t)ray * 4 + lane] = v;
}

extern "C" void kernel_launch(void* const* d_in, const int* in_sizes, int n_in,
                              void* d_out, int out_size, void* d_ws, size_t ws_size,
                              hipStream_t stream) {
    const float* depth   = (const float*)d_in[0];
    const float* density = (const float*)d_in[1];
    const float* feature = (const float*)d_in[2];
    float* out = (float*)d_out;

    int num_rays = in_sizes[0] / P;          // 65536
    const int waves_per_block = 4;           // 256 threads
    int blocks = (num_rays + waves_per_block - 1) / waves_per_block;
    volrender_kernel<<<blocks, 256, 0, stream>>>(depth, density, feature, out, num_rays);
}